// Round 2
// baseline (1638.036 us; speedup 1.0000x reference)
//
#include <hip/hip_runtime.h>

#define TT 8000
#define NB 4

__device__ __forceinline__ int rfl(int v){ return __builtin_amdgcn_readfirstlane(v); }

// ---------------- prep: transpose weights to [k][c] layouts ----------------
// dT  [16][64][2][128]  from dil_w  [16][128][64][2]
// cT  [16][80][128]     from cond_w [2048][80]
// rT  [15][64][64]      from res_w  [15][64][64]   (swap last two)
// sT  [16][64][256]     from skip_w [16][256][64]
// coT [256][256]        from conv_out_w [256][256] (transpose)
// ceT [256][256]        from conv_end_w [256][256]
__global__ void prep_kernel(const float* __restrict__ dil_w, const float* __restrict__ cond_w,
                            const float* __restrict__ res_w, const float* __restrict__ skip_w,
                            const float* __restrict__ cow, const float* __restrict__ cew,
                            float* __restrict__ dT, float* __restrict__ cT, float* __restrict__ rT,
                            float* __restrict__ sT, float* __restrict__ coT, float* __restrict__ ceT)
{
  int g = blockIdx.x*256 + threadIdx.x;
  if (g < 262144){
    int idx = g;
    int c2 = idx & 127, tap = (idx>>7)&1, r = (idx>>8)&63, i = idx>>14;
    dT[idx] = dil_w[((i*128+c2)*64+r)*2+tap];
  } else if (g < 262144+163840){
    int idx = g - 262144;
    int c2 = idx & 127, o = (idx>>7)%80, i = idx/10240;
    cT[idx] = cond_w[(i*128+c2)*80+o];
  } else if (g < 262144+163840+61440){
    int idx = g - (262144+163840);
    int r = idx & 63, k = (idx>>6)&63, i = idx>>12;
    rT[idx] = res_w[(i*64+r)*64+k];
  } else if (g < 262144+163840+61440+262144){
    int idx = g - (262144+163840+61440);
    int c = idx & 255, k = (idx>>8)&63, i = idx>>14;
    sT[idx] = skip_w[(i*256+c)*64+k];
  } else if (g < 262144+163840+61440+262144+65536){
    int idx = g - (262144+163840+61440+262144);
    int c = idx & 255, k = idx>>8;
    coT[idx] = cow[c*256+k];
  } else if (g < 262144+163840+61440+262144+131072){
    int idx = g - (262144+163840+61440+262144+65536);
    int c = idx & 255, k = idx>>8;
    ceT[idx] = cew[c*256+k];
  }
}

// ---------------- upsample ----------------
// cond[n][o][t] = up_b[o] + sum_{i,s} feat[n][i][s] * up_w[o][i][t-256s], k=t-256s in [0,1024)
// (conv_transpose with transpose_kernel=True: first dim of up_w indexed by OUTPUT channel)
__global__ __launch_bounds__(256) void upsample_kernel(
    const float* __restrict__ feat, const float* __restrict__ up_w,
    const float* __restrict__ up_b, float* __restrict__ cond)
{
  int tc = blockIdx.x, o = blockIdx.y, n = blockIdx.z;
  int tid = threadIdx.x;
  int t = tc*256 + tid;
  float acc = up_b[o];
  #pragma unroll
  for (int ds=0; ds<4; ds++){
    int s = tc - ds;
    if (s >= 0){
      // k = t - 256*s = 256*ds + tid, always in [0,1024)
      const float* wb = up_w + (size_t)o*81920 + 256*ds + tid;   // up_w[o][i][k], stride i -> 1024
      const float* fb = feat + (size_t)n*80*32 + s;
      for (int i=0;i<80;i++)
        acc = __fmaf_rn(fb[(size_t)i*32], wb[(size_t)i*1024], acc);
    }
  }
  if (t < TT) cond[((size_t)n*80+o)*TT + t] = acc;
}

// ---------------- embedding: x[n][r][t] = embed[fi[n][t]][r]
__global__ __launch_bounds__(256) void embed_kernel(
    const int* __restrict__ fi, const float* __restrict__ embed, float* __restrict__ x)
{
  int tile = blockIdx.x; int n = blockIdx.y;
  int lane = threadIdx.x & 63, grp = threadIdx.x >> 6;
  int t = tile*64 + lane;
  int idx = fi[(size_t)n*TT + t];
  const float* er = embed + (size_t)idx*64 + grp*16;
  float* xp = x + ((size_t)n*64 + grp*16)*TT + t;
  #pragma unroll
  for (int r=0;r<16;r++) xp[(size_t)r*TT] = er[r];
}

// ---------------- one residual layer ----------------
// block = 256 thr = 4 waves; lane = t within 64-wide tile; wave w owns:
//   phase A: in_act channels [32w, 32w+32)
//   phase B: skip channels [64w, 64w+64), res channels [16w, 16w+16)
template<bool FIRST, bool LAST>
__global__ __launch_bounds__(256) void layer_kernel(
    const float* __restrict__ x_in, float* __restrict__ x_out,
    const float* __restrict__ cond, float* __restrict__ skipb,
    const float* __restrict__ dT,    // [64][2][128] layer slice
    const float* __restrict__ dil_b, // [128]
    const float* __restrict__ cT,    // [80][128]
    const float* __restrict__ cond_b,// [128]
    const float* __restrict__ rT,    // [64][64]
    const float* __restrict__ res_b, // [64]
    const float* __restrict__ sT,    // [64][256]
    const float* __restrict__ skip_b,// [256]
    int d)
{
  __shared__ float ex[64][65];
  int bx = blockIdx.x;
  int tile = bx % 125, n = bx / 125;
  int lane = threadIdx.x & 63;
  int wave = rfl(threadIdx.x >> 6);
  int t = tile*64 + lane;
  const float* xn = x_in + (size_t)n*64*TT;
  const float* cn = cond + (size_t)n*80*TT;
  int c2base = wave*32;

  // ---- phase A: in_act[c2base+j][t] ----
  float acc[32];
  #pragma unroll
  for (int j=0;j<32;j++) acc[j] = dil_b[c2base+j] + cond_b[c2base+j];

  int td = t - d;
  for (int k=0;k<64;k++){
    float xtk = xn[(size_t)k*TT + t];
    float xdk = (td >= 0) ? xn[(size_t)k*TT + td] : 0.f;
    const float* w0 = dT + k*256 + c2base;      // tap0 -> x[t-d]
    const float* w1 = w0 + 128;                 // tap1 -> x[t]
    #pragma unroll
    for (int j=0;j<32;j++) acc[j] = __fmaf_rn(w0[j], xdk, acc[j]);
    #pragma unroll
    for (int j=0;j<32;j++) acc[j] = __fmaf_rn(w1[j], xtk, acc[j]);
  }
  for (int o=0;o<80;o++){
    float cv = cn[(size_t)o*TT + t];
    const float* wc = cT + o*128 + c2base;
    #pragma unroll
    for (int j=0;j<32;j++) acc[j] = __fmaf_rn(wc[j], cv, acc[j]);
  }

  // ---- gate: acts[r] = tanh(ia[r]) * sigmoid(ia[r+64]) ----
  if (wave >= 2){
    #pragma unroll
    for (int j=0;j<32;j++) ex[c2base-64+j][lane] = acc[j];
  }
  __syncthreads();
  if (wave < 2){
    #pragma unroll
    for (int j=0;j<32;j++){
      float a = acc[j];
      a = fminf(fmaxf(a, -20.f), 20.f);
      float b = ex[c2base+j][lane];
      float e2a = __expf(2.f*a);
      float th = __fdividef(e2a - 1.f, e2a + 1.f);
      float sg = __fdividef(1.f, 1.f + __expf(-b));
      ex[c2base+j][lane] = th * sg;
    }
  }
  __syncthreads();

  // ---- phase B: skip (64 ch/wave) + res (16 ch/wave) ----
  int cb = wave*64;
  int rb = wave*16;
  float sacc[64];
  #pragma unroll
  for (int j=0;j<64;j++) sacc[j] = skip_b[cb+j];
  float racc[16];
  if (!LAST){
    #pragma unroll
    for (int j=0;j<16;j++) racc[j] = res_b[rb+j];
  }
  for (int k=0;k<64;k++){
    float a = ex[k][lane];
    const float* wsk = sT + k*256 + cb;
    #pragma unroll
    for (int j=0;j<64;j++) sacc[j] = __fmaf_rn(wsk[j], a, sacc[j]);
    if (!LAST){
      const float* wr = rT + k*64 + rb;
      #pragma unroll
      for (int j=0;j<16;j++) racc[j] = __fmaf_rn(wr[j], a, racc[j]);
    }
  }
  if (!LAST){
    float* xo = x_out + (size_t)n*64*TT;
    #pragma unroll
    for (int j=0;j<16;j++) xo[(size_t)(rb+j)*TT + t] = racc[j] + xn[(size_t)(rb+j)*TT + t];
  }
  float* sp = skipb + ((size_t)n*256 + cb)*TT + t;
  #pragma unroll
  for (int j=0;j<64;j++){
    if (FIRST) sp[(size_t)j*TT] = sacc[j];
    else       sp[(size_t)j*TT] += sacc[j];
  }
}

// ---------------- output convs: out[c][t] = sum_k WT[k][c] * relu(in[k][t]) ----------------
__global__ __launch_bounds__(256) void outconv_kernel(
    const float* __restrict__ in, const float* __restrict__ WT, float* __restrict__ out)
{
  int tile = blockIdx.x % 125, n = blockIdx.x / 125;
  int lane = threadIdx.x & 63;
  int wave = rfl(threadIdx.x >> 6);
  int t = tile*64 + lane;
  int cb = wave*64;
  const float* inb = in + (size_t)n*256*TT + t;
  float acc[64];
  #pragma unroll
  for (int j=0;j<64;j++) acc[j] = 0.f;
  for (int k=0;k<256;k++){
    float v = fmaxf(inb[(size_t)k*TT], 0.f);
    const float* w = WT + k*256 + cb;
    #pragma unroll
    for (int j=0;j<64;j++) acc[j] = __fmaf_rn(w[j], v, acc[j]);
  }
  float* ob = out + ((size_t)n*256 + cb)*TT + t;
  #pragma unroll
  for (int j=0;j<64;j++) ob[(size_t)j*TT] = acc[j];
}

// ---------------- shift by one sample ----------------
__global__ __launch_bounds__(256) void shift_kernel(const float* __restrict__ in, float* __restrict__ out)
{
  size_t i = (size_t)blockIdx.x*256 + threadIdx.x;
  if (i < (size_t)NB*256*TT){
    int tpos = (int)(i % TT);
    out[i] = (tpos == 0) ? 0.f : in[i-1];
  }
}

extern "C" void kernel_launch(void* const* d_in, const int* in_sizes, int n_in,
                              void* d_out, int out_size, void* d_ws, size_t ws_size,
                              hipStream_t stream)
{
  const float* feat   = (const float*)d_in[0];
  const int*   fi     = (const int*)  d_in[1];
  const float* embed  = (const float*)d_in[2];
  const float* up_w   = (const float*)d_in[3];
  const float* up_b   = (const float*)d_in[4];
  const float* cond_w = (const float*)d_in[5];
  const float* cond_b = (const float*)d_in[6];
  const float* dil_w  = (const float*)d_in[7];
  const float* dil_b  = (const float*)d_in[8];
  const float* res_w  = (const float*)d_in[9];
  const float* res_b  = (const float*)d_in[10];
  const float* skip_w = (const float*)d_in[11];
  const float* skip_b = (const float*)d_in[12];
  const float* cow    = (const float*)d_in[13];
  const float* cew    = (const float*)d_in[14];
  float* out = (float*)d_out;
  float* ws  = (float*)d_ws;

  float* cond  = ws;                  // 2,560,000
  float* xA    = cond + 2560000;      // 2,048,000
  float* xB    = xA + 2048000;        // 2,048,000
  float* skipb = xB + 2048000;        // 8,192,000
  float* dT    = skipb + 8192000;     // 262,144
  float* cT    = dT + 262144;         // 163,840
  float* rT    = cT + 163840;         //  61,440
  float* sT    = rT + 61440;          // 262,144
  float* coT   = sT + 262144;         //  65,536
  float* ceT   = coT + 65536;         //  65,536

  prep_kernel<<<3440, 256, 0, stream>>>(dil_w, cond_w, res_w, skip_w, cow, cew,
                                        dT, cT, rT, sT, coT, ceT);
  upsample_kernel<<<dim3(32,80,4), 256, 0, stream>>>(feat, up_w, up_b, cond);
  embed_kernel<<<dim3(125,4), 256, 0, stream>>>(fi, embed, xA);

  const float* xin = xA; float* xout = xB;
  for (int i=0;i<16;i++){
    int dd = 1 << (i & 7);
    const float* dTi = dT + i*16384;
    const float* cTi = cT + i*10240;
    const float* rTi = rT + (i<15 ? i*4096 : 0);
    const float* rbi = res_b + (i<15 ? i*64 : 0);
    const float* sTi = sT + i*16384;
    if (i == 0)
      layer_kernel<true,false><<<500,256,0,stream>>>(xin, xout, cond, skipb, dTi, dil_b+i*128,
          cTi, cond_b+i*128, rTi, rbi, sTi, skip_b+i*256, dd);
    else if (i == 15)
      layer_kernel<false,true><<<500,256,0,stream>>>(xin, xout, cond, skipb, dTi, dil_b+i*128,
          cTi, cond_b+i*128, rTi, rbi, sTi, skip_b+i*256, dd);
    else
      layer_kernel<false,false><<<500,256,0,stream>>>(xin, xout, cond, skipb, dTi, dil_b+i*128,
          cTi, cond_b+i*128, rTi, rbi, sTi, skip_b+i*256, dd);
    const float* nin = xout;
    xout = (float*)xin;
    xin = nin;
  }

  outconv_kernel<<<500,256,0,stream>>>(skipb, coT, out);   // relu(skip) @ conv_out -> raw
  outconv_kernel<<<500,256,0,stream>>>(out, ceT, skipb);   // relu(prev) @ conv_end
  shift_kernel<<<32000,256,0,stream>>>(skipb, out);        // one-sample delay
}

// Round 3
// 600.308 us; speedup vs baseline: 2.7287x; 2.7287x over previous
//
#include <hip/hip_runtime.h>
#include <cstdint>

#define TT 8000
#define NB 4

typedef _Float16 half8 __attribute__((ext_vector_type(8)));
typedef float f32x4 __attribute__((ext_vector_type(4)));

static __device__ __forceinline__ f32x4 MFMA16(half8 a, half8 b, f32x4 c){
  return __builtin_amdgcn_mfma_f32_16x16x32_f16(a, b, c, 0, 0, 0);
}

static __device__ __forceinline__ float gatef(float a, float b){
  a = fminf(fmaxf(a, -20.f), 20.f);
  float e2a = __expf(2.f*a);
  float th = __fdividef(e2a - 1.f, e2a + 1.f);
  float sg = __fdividef(1.f, 1.f + __expf(-b));
  return th * sg;
}

union PK4 { uint64_t u; _Float16 h[4]; };

// ---------------- prep: convert/pack all weights to f16 MFMA-A layouts ----------------
// WdT [16][2][128][64] : WdT[l][tap][m=c2][k=r] = dil_w[l][c2][r][tap]
// Wc  [16][128][96]    : Wc[l][c2][o<80] = cond_w[l*128+c2][o], pad 0
// Wr  [15][64][64]     : res_w as-is (row [o][i]) cvt
// Wsa [256][1024]      : Wsa[m][l*64+j] = skip_w[l][m][j]
// Wco/Wce [256][256]   : cvt (row-major [o][i])
// bsum[256] fp32       : sum_l skip_b[l][c]
__global__ void prep_kernel(const float* __restrict__ dil_w, const float* __restrict__ cond_w,
                            const float* __restrict__ res_w, const float* __restrict__ skip_w,
                            const float* __restrict__ cow, const float* __restrict__ cew,
                            const float* __restrict__ skip_b,
                            _Float16* __restrict__ WdT, _Float16* __restrict__ Wc,
                            _Float16* __restrict__ Wr, _Float16* __restrict__ Wsa,
                            _Float16* __restrict__ Wco, _Float16* __restrict__ Wce,
                            float* __restrict__ bsum)
{
  int g = blockIdx.x*256 + threadIdx.x;
  if (g < 262144){
    int r = g & 63, m = (g>>6) & 127, tap = (g>>13) & 1, l = g>>14;
    WdT[g] = (_Float16)dil_w[(((l*128+m)*64 + r)*2) + tap];
  } else if ((g -= 262144) < 196608){
    int o = g % 96; int rest = g / 96; int m = rest & 127; int l = rest >> 7;
    Wc[g] = (_Float16)((o < 80) ? cond_w[(l*128+m)*80 + o] : 0.f);
  } else if ((g -= 196608) < 61440){
    Wr[g] = (_Float16)res_w[g];
  } else if ((g -= 61440) < 262144){
    int kk = g & 1023, m = g >> 10; int l = kk >> 6, j = kk & 63;
    Wsa[g] = (_Float16)skip_w[(l*256+m)*64 + j];
  } else if ((g -= 262144) < 65536){
    Wco[g] = (_Float16)cow[g];
  } else if ((g -= 65536) < 65536){
    Wce[g] = (_Float16)cew[g];
  } else if ((g -= 65536) < 256){
    float s = 0.f;
    for (int l = 0; l < 16; l++) s += skip_b[l*256 + g];
    bsum[g] = s;
  }
}

// ---------------- upsample: block (tc,o), all 4 batches per thread (4x weight reuse) ----
// cond[n][o][t] = up_b[o] + sum_{i,ds} feat[n][i][tc-ds] * up_w[o][i][256ds+tid]
__global__ __launch_bounds__(256) void upsample_kernel(
    const float* __restrict__ feat, const float* __restrict__ up_w,
    const float* __restrict__ up_b, float* __restrict__ condf)
{
  int tc = blockIdx.x, o = blockIdx.y, tid = threadIdx.x;
  int t = tc*256 + tid;
  float ub = up_b[o];
  float a0 = ub, a1 = ub, a2 = ub, a3 = ub;
  #pragma unroll
  for (int ds = 0; ds < 4; ds++){
    int s = tc - ds;
    if (s >= 0){
      const float* wb = up_w + (size_t)o*81920 + 256*ds + tid;
      const float* fb = feat + s;
      for (int i = 0; i < 80; i++){
        float wv = wb[(size_t)i*1024];
        a0 = __fmaf_rn(wv, fb[(size_t)(0*80+i)*32], a0);
        a1 = __fmaf_rn(wv, fb[(size_t)(1*80+i)*32], a1);
        a2 = __fmaf_rn(wv, fb[(size_t)(2*80+i)*32], a2);
        a3 = __fmaf_rn(wv, fb[(size_t)(3*80+i)*32], a3);
      }
    }
  }
  if (t < TT){
    condf[((size_t)(0*80+o))*TT + t] = a0;
    condf[((size_t)(1*80+o))*TT + t] = a1;
    condf[((size_t)(2*80+o))*TT + t] = a2;
    condf[((size_t)(3*80+o))*TT + t] = a3;
  }
}

// ---------------- condpack: cond fp32 [n][80][T] -> f16 [n][T][96] (pad 0) ------------
__global__ __launch_bounds__(256) void condpack_kernel(
    const float* __restrict__ condf, _Float16* __restrict__ condh)
{
  __shared__ float ls[64*101];
  int t0 = blockIdx.x*64, n = blockIdx.y, tid = threadIdx.x;
  for (int e = tid; e < 5120; e += 256){
    int ch = e >> 6, tl = e & 63;
    ls[tl*101 + ch] = condf[((size_t)(n*80+ch))*TT + t0 + tl];
  }
  __syncthreads();
  uint32_t* dst = (uint32_t*)condh;
  for (int e = tid; e < 3072; e += 256){
    int tl = e / 48, cp = e % 48; int c0 = cp*2;
    float f0 = (c0   < 80) ? ls[tl*101 + c0]   : 0.f;
    float f1 = (c0+1 < 80) ? ls[tl*101 + c0+1] : 0.f;
    _Float16 h0 = (_Float16)f0, h1 = (_Float16)f1;
    uint16_t u0 = *(uint16_t*)&h0, u1 = *(uint16_t*)&h1;
    dst[((size_t)n*TT + t0 + tl)*48 + cp] = ((uint32_t)u1 << 16) | u0;
  }
}

// ---------------- embedding: x[n][r][t] = embed[fi[n][t]][r] (fp32) -------------------
__global__ __launch_bounds__(256) void embed_kernel(
    const int* __restrict__ fi, const float* __restrict__ embed, float* __restrict__ x)
{
  int tile = blockIdx.x; int n = blockIdx.y;
  int lane = threadIdx.x & 63, grp = threadIdx.x >> 6;
  int t = tile*64 + lane;
  int idx = fi[(size_t)n*TT + t];
  const float* er = embed + (size_t)idx*64 + grp*16;
  float* xp = x + ((size_t)n*64 + grp*16)*TT + t;
  #pragma unroll
  for (int r = 0; r < 16; r++) xp[(size_t)r*TT] = er[r];
}

// ---------------- one residual layer, f16 MFMA ----------------
// block 256 = 4 waves, t-tile 64.  Wave w owns in_act M-tiles {w, w+4} so the
// tanh row (16w+..) and sigmoid row (64+16w+..) are in the same wave's accs.
// acts -> XOR-swizzled LDS tile [t][64] f16 -> B-frags for res GEMM; also stored
// to global actsG [n][t][1024] (slice l*64) for the fused final skip GEMM.
template<bool LAST>
__global__ __launch_bounds__(256) void layer_mfma(
    const float* __restrict__ xin, float* __restrict__ xout,
    const _Float16* __restrict__ condh,   // [n][t][96]
    _Float16* __restrict__ actsL,         // actsG + l*64
    const _Float16* __restrict__ WdT,     // [2][128][64]
    const _Float16* __restrict__ Wc,      // [128][96]
    const _Float16* __restrict__ Wr,      // [64][64]
    const float* __restrict__ dil_b_l,    // [128]
    const float* __restrict__ cond_b_l,   // [128]
    const float* __restrict__ res_b_l,    // [64]
    int d)
{
  __shared__ __attribute__((aligned(16))) char als[8192];  // [64 t][64 ch] f16, swizzled
  int bx = blockIdx.x;
  int tile = bx % 125, n = bx / 125;
  int tid = threadIdx.x;
  int lane = tid & 63;
  int w = tid >> 6;
  int t0 = tile*64;
  int l16 = lane & 15;
  int lg  = lane >> 4;
  const float* xn = xin + (size_t)n*64*TT;

  // ---- A fragments (all L2-resident weight reads) ----
  half8 aD[2][2][2];   // [tap][mi][ks]
  half8 aC[2][3];      // [mi][kc]
  #pragma unroll
  for (int mi = 0; mi < 2; mi++){
    int m = (w + 4*mi)*16 + l16;
    #pragma unroll
    for (int tap = 0; tap < 2; tap++)
      #pragma unroll
      for (int ks = 0; ks < 2; ks++)
        aD[tap][mi][ks] = *(const half8*)(WdT + ((size_t)(tap*128 + m)*64 + ks*32 + lg*8));
    #pragma unroll
    for (int kc = 0; kc < 3; kc++)
      aC[mi][kc] = *(const half8*)(Wc + ((size_t)m*96 + kc*32 + lg*8));
  }
  float bias[2][4];
  #pragma unroll
  for (int mi = 0; mi < 2; mi++)
    #pragma unroll
    for (int r = 0; r < 4; r++){
      int mm = (w + 4*mi)*16 + lg*4 + r;
      bias[mi][r] = dil_b_l[mm] + cond_b_l[mm];
    }

  f32x4 acc[2][4];
  #pragma unroll
  for (int nt = 0; nt < 4; nt++){
    int t = t0 + nt*16 + l16;
    int td = t - d;
    half8 bcur[2], bdel[2], bcnd[3];
    #pragma unroll
    for (int ks = 0; ks < 2; ks++){
      const float* xc = xn + (size_t)(ks*32 + lg*8)*TT + t;
      #pragma unroll
      for (int j = 0; j < 8; j++) bcur[ks][j] = (_Float16)xc[(size_t)j*TT];
      const float* xd = xn + (size_t)(ks*32 + lg*8)*TT + td;
      #pragma unroll
      for (int j = 0; j < 8; j++) bdel[ks][j] = (_Float16)((td >= 0) ? xd[(size_t)j*TT] : 0.f);
    }
    #pragma unroll
    for (int kc = 0; kc < 3; kc++)
      bcnd[kc] = *(const half8*)(condh + ((size_t)n*TT + t)*96 + kc*32 + lg*8);

    #pragma unroll
    for (int mi = 0; mi < 2; mi++){
      f32x4 a; a[0]=bias[mi][0]; a[1]=bias[mi][1]; a[2]=bias[mi][2]; a[3]=bias[mi][3];
      a = MFMA16(aD[0][mi][0], bdel[0], a);
      a = MFMA16(aD[0][mi][1], bdel[1], a);
      a = MFMA16(aD[1][mi][0], bcur[0], a);
      a = MFMA16(aD[1][mi][1], bcur[1], a);
      a = MFMA16(aC[mi][0], bcnd[0], a);
      a = MFMA16(aC[mi][1], bcnd[1], a);
      a = MFMA16(aC[mi][2], bcnd[2], a);
      acc[mi][nt] = a;
    }
  }

  // ---- gate + acts (f16) -> LDS (swizzled) + global ----
  int ch0 = w*16 + lg*4;
  #pragma unroll
  for (int nt = 0; nt < 4; nt++){
    int tl = nt*16 + l16;
    PK4 pk;
    #pragma unroll
    for (int r = 0; r < 4; r++)
      pk.h[r] = (_Float16)gatef(acc[0][nt][r], acc[1][nt][r]);
    if (!LAST)
      *(uint64_t*)(als + tl*128 + ((ch0*2) ^ ((tl & 7) << 4))) = pk.u;
    *(uint64_t*)(actsL + ((size_t)n*TT + t0 + tl)*1024 + ch0) = pk.u;
  }

  if (!LAST){
    __syncthreads();
    // ---- res GEMM: x_out = Wr @ acts + res_b + x_in ----
    half8 aR[2];
    int mr = w*16 + l16;
    #pragma unroll
    for (int ks = 0; ks < 2; ks++)
      aR[ks] = *(const half8*)(Wr + (size_t)mr*64 + ks*32 + lg*8);
    float rb[4];
    #pragma unroll
    for (int r = 0; r < 4; r++) rb[r] = res_b_l[w*16 + lg*4 + r];
    float* xo = xout + (size_t)n*64*TT;
    #pragma unroll
    for (int nt = 0; nt < 4; nt++){
      int tl = nt*16 + l16; int t = t0 + tl;
      half8 bA[2];
      #pragma unroll
      for (int ks = 0; ks < 2; ks++)
        bA[ks] = *(const half8*)(als + tl*128 + (((ks*32 + lg*8)*2) ^ ((tl & 7) << 4)));
      f32x4 rc; rc[0]=rb[0]; rc[1]=rb[1]; rc[2]=rb[2]; rc[3]=rb[3];
      rc = MFMA16(aR[0], bA[0], rc);
      rc = MFMA16(aR[1], bA[1], rc);
      #pragma unroll
      for (int r = 0; r < 4; r++){
        int m = w*16 + lg*4 + r;
        xo[(size_t)m*TT + t] = rc[r] + xn[(size_t)m*TT + t];
      }
    }
  }
}

// ---------------- fused final: skip-sum(K=1024) -> relu -> conv_out -> relu -> conv_end -> shift
__global__ __launch_bounds__(256) void final_fused(
    const _Float16* __restrict__ actsG,  // [n][t][1024]
    const _Float16* __restrict__ Wsa,    // [256][1024]
    const _Float16* __restrict__ Wco,    // [256][256]
    const _Float16* __restrict__ Wce,    // [256][256]
    const float* __restrict__ bsum,      // [256]
    float* __restrict__ out)             // [n][256][8000]
{
  __shared__ __attribute__((aligned(16))) char ls[32768]; // [64 t][256 ch] f16, swizzled
  int bx = blockIdx.x;
  int tile = bx % 125, n = bx / 125;
  int tid = threadIdx.x;
  int lane = tid & 63;
  int w = tid >> 6;
  int t0 = tile*64;
  int l16 = lane & 15;
  int lg  = lane >> 4;

  // phase 1: skip sum GEMM, wave w owns M-tiles 4w..4w+3 (rows 64w..64w+63)
  f32x4 acc[4][4]; // [mi][nt]
  #pragma unroll
  for (int mi = 0; mi < 4; mi++)
    #pragma unroll
    for (int nt = 0; nt < 4; nt++){
      f32x4 a;
      #pragma unroll
      for (int r = 0; r < 4; r++) a[r] = bsum[(4*w+mi)*16 + lg*4 + r];
      acc[mi][nt] = a;
    }
  for (int ks = 0; ks < 32; ks++){
    half8 bf[4];
    #pragma unroll
    for (int nt = 0; nt < 4; nt++){
      int t = t0 + nt*16 + l16;
      bf[nt] = *(const half8*)(actsG + ((size_t)n*TT + t)*1024 + ks*32 + lg*8);
    }
    #pragma unroll
    for (int mi = 0; mi < 4; mi++){
      int m = (4*w+mi)*16 + l16;
      half8 af = *(const half8*)(Wsa + (size_t)m*1024 + ks*32 + lg*8);
      #pragma unroll
      for (int nt = 0; nt < 4; nt++) acc[mi][nt] = MFMA16(af, bf[nt], acc[mi][nt]);
    }
  }
  // relu -> LDS
  #pragma unroll
  for (int mi = 0; mi < 4; mi++){
    int c0 = (4*w+mi)*16 + lg*4;
    #pragma unroll
    for (int nt = 0; nt < 4; nt++){
      int tl = nt*16 + l16;
      PK4 pk;
      #pragma unroll
      for (int r = 0; r < 4; r++) pk.h[r] = (_Float16)fmaxf(acc[mi][nt][r], 0.f);
      *(uint64_t*)(ls + tl*512 + ((c0*2) ^ ((tl & 7) << 4))) = pk.u;
    }
  }
  __syncthreads();

  // phase 2: conv_out (K=256)
  #pragma unroll
  for (int mi = 0; mi < 4; mi++)
    #pragma unroll
    for (int nt = 0; nt < 4; nt++){ f32x4 a; a[0]=0;a[1]=0;a[2]=0;a[3]=0; acc[mi][nt]=a; }
  #pragma unroll
  for (int ks = 0; ks < 8; ks++){
    half8 bf[4];
    #pragma unroll
    for (int nt = 0; nt < 4; nt++){
      int tl = nt*16 + l16;
      bf[nt] = *(const half8*)(ls + tl*512 + (((ks*32 + lg*8)*2) ^ ((tl & 7) << 4)));
    }
    #pragma unroll
    for (int mi = 0; mi < 4; mi++){
      int m = (4*w+mi)*16 + l16;
      half8 af = *(const half8*)(Wco + (size_t)m*256 + ks*32 + lg*8);
      #pragma unroll
      for (int nt = 0; nt < 4; nt++) acc[mi][nt] = MFMA16(af, bf[nt], acc[mi][nt]);
    }
  }
  __syncthreads();
  #pragma unroll
  for (int mi = 0; mi < 4; mi++){
    int c0 = (4*w+mi)*16 + lg*4;
    #pragma unroll
    for (int nt = 0; nt < 4; nt++){
      int tl = nt*16 + l16;
      PK4 pk;
      #pragma unroll
      for (int r = 0; r < 4; r++) pk.h[r] = (_Float16)fmaxf(acc[mi][nt][r], 0.f);
      *(uint64_t*)(ls + tl*512 + ((c0*2) ^ ((tl & 7) << 4))) = pk.u;
    }
  }
  __syncthreads();

  // phase 3: conv_end (K=256) + shifted store
  #pragma unroll
  for (int mi = 0; mi < 4; mi++)
    #pragma unroll
    for (int nt = 0; nt < 4; nt++){ f32x4 a; a[0]=0;a[1]=0;a[2]=0;a[3]=0; acc[mi][nt]=a; }
  #pragma unroll
  for (int ks = 0; ks < 8; ks++){
    half8 bf[4];
    #pragma unroll
    for (int nt = 0; nt < 4; nt++){
      int tl = nt*16 + l16;
      bf[nt] = *(const half8*)(ls + tl*512 + (((ks*32 + lg*8)*2) ^ ((tl & 7) << 4)));
    }
    #pragma unroll
    for (int mi = 0; mi < 4; mi++){
      int m = (4*w+mi)*16 + l16;
      half8 af = *(const half8*)(Wce + (size_t)m*256 + ks*32 + lg*8);
      #pragma unroll
      for (int nt = 0; nt < 4; nt++) acc[mi][nt] = MFMA16(af, bf[nt], acc[mi][nt]);
    }
  }
  #pragma unroll
  for (int mi = 0; mi < 4; mi++)
    #pragma unroll
    for (int nt = 0; nt < 4; nt++)
      #pragma unroll
      for (int r = 0; r < 4; r++){
        int m = (4*w+mi)*16 + lg*4 + r;
        int t = t0 + nt*16 + l16;
        size_t ob = ((size_t)n*256 + m)*TT;
        if (t + 1 < TT) out[ob + t + 1] = acc[mi][nt][r];
        if (t == 0)     out[ob] = 0.f;
      }
}

extern "C" void kernel_launch(void* const* d_in, const int* in_sizes, int n_in,
                              void* d_out, int out_size, void* d_ws, size_t ws_size,
                              hipStream_t stream)
{
  const float* feat   = (const float*)d_in[0];
  const int*   fi     = (const int*)  d_in[1];
  const float* embed  = (const float*)d_in[2];
  const float* up_w   = (const float*)d_in[3];
  const float* up_b   = (const float*)d_in[4];
  const float* cond_w = (const float*)d_in[5];
  const float* cond_b = (const float*)d_in[6];
  const float* dil_w  = (const float*)d_in[7];
  const float* dil_b  = (const float*)d_in[8];
  const float* res_w  = (const float*)d_in[9];
  const float* res_b  = (const float*)d_in[10];
  const float* skip_w = (const float*)d_in[11];
  const float* skip_b = (const float*)d_in[12];
  const float* cow    = (const float*)d_in[13];
  const float* cew    = (const float*)d_in[14];
  float* out = (float*)d_out;
  float* cur = (float*)d_ws;

  float*     xA    = cur;               cur += 2048000;
  float*     xB    = cur;               cur += 2048000;
  _Float16*  condh = (_Float16*)cur;    cur += 1536000;   // [4][8000][96] f16
  _Float16*  WdT   = (_Float16*)cur;    cur += 131072;    // 262144 f16
  _Float16*  Wc    = (_Float16*)cur;    cur += 98304;     // 196608 f16
  _Float16*  Wr    = (_Float16*)cur;    cur += 30720;     // 61440 f16
  _Float16*  Wsa   = (_Float16*)cur;    cur += 131072;    // 262144 f16
  _Float16*  Wco   = (_Float16*)cur;    cur += 32768;
  _Float16*  Wce   = (_Float16*)cur;    cur += 32768;
  float*     bsum  = cur;               cur += 256;
  _Float16*  actsG = (_Float16*)cur;                      // [4][8000][1024] f16 (32.77M)
  float*     condf = cur;               // overlay: cond fp32 dead before actsG written

  prep_kernel<<<3569, 256, 0, stream>>>(dil_w, cond_w, res_w, skip_w, cow, cew, skip_b,
                                        WdT, Wc, Wr, Wsa, Wco, Wce, bsum);
  upsample_kernel<<<dim3(32,80), 256, 0, stream>>>(feat, up_w, up_b, condf);
  condpack_kernel<<<dim3(125,4), 256, 0, stream>>>(condf, condh);
  embed_kernel<<<dim3(125,4), 256, 0, stream>>>(fi, embed, xA);

  const float* xin = xA; float* xout = xB;
  for (int l = 0; l < 16; l++){
    int dd = 1 << (l & 7);
    const _Float16* WdTl = WdT + (size_t)l*16384;
    const _Float16* Wcl  = Wc  + (size_t)l*12288;
    const _Float16* Wrl  = Wr  + (size_t)(l < 15 ? l : 0)*4096;
    const float*    rbl  = res_b + (size_t)(l < 15 ? l : 0)*64;
    _Float16* actsL = actsG + (size_t)l*64;
    if (l == 15)
      layer_mfma<true><<<500, 256, 0, stream>>>((const float*)xin, xout, condh, actsL,
          WdTl, Wcl, Wrl, dil_b + l*128, cond_b + l*128, rbl, dd);
    else
      layer_mfma<false><<<500, 256, 0, stream>>>((const float*)xin, xout, condh, actsL,
          WdTl, Wcl, Wrl, dil_b + l*128, cond_b + l*128, rbl, dd);
    const float* nin = xout; xout = (float*)xin; xin = nin;
  }

  final_fused<<<500, 256, 0, stream>>>(actsG, Wsa, Wco, Wce, bsum, out);
}